// Round 12
// baseline (536.770 us; speedup 1.0000x reference)
//
#include <hip/hip_runtime.h>
#include <hip/hip_bf16.h>
#include <math.h>

#define HID 64
#define TSEQ 96
#define NOUT 96
#define NIN 5
#define FLATN (TSEQ * NOUT)   // 9216
#define PSTEPS 960            // probes: 10x the real step count

#define LOG2E 1.4426950408889634f

typedef float f32x4 __attribute__((ext_vector_type(4)));

__device__ __forceinline__ float fast_sigmoid(float x) {
    return __builtin_amdgcn_rcpf(1.0f + __builtin_amdgcn_exp2f(-LOG2E * x));
}

__device__ __forceinline__ float fast_tanh(float x) {
    const float ax = fabsf(x);
    const float e = __builtin_amdgcn_exp2f(-2.0f * LOG2E * ax);
    const float t = (1.0f - e) * __builtin_amdgcn_rcpf(1.0f + e);
    return copysignf(t, x);
}

__device__ __forceinline__ float bcast(float v, int l) {
    return __uint_as_float(__builtin_amdgcn_readlane(__float_as_uint(v), l));
}

#define LOAD_W_AND_PIN(SRC)                                                    \
    const f32x4* __restrict__ Wrow = reinterpret_cast<const f32x4*>((SRC) + tid * HID); \
    f32x4 w0 = Wrow[0],  w1 = Wrow[1],  w2 = Wrow[2],  w3 = Wrow[3];           \
    f32x4 w4 = Wrow[4],  w5 = Wrow[5],  w6 = Wrow[6],  w7 = Wrow[7];           \
    f32x4 w8 = Wrow[8],  w9 = Wrow[9],  w10 = Wrow[10], w11 = Wrow[11];        \
    f32x4 w12 = Wrow[12], w13 = Wrow[13], w14 = Wrow[14], w15 = Wrow[15];      \
    asm volatile("" : "+v"(w0), "+v"(w1), "+v"(w2), "+v"(w3),                  \
                      "+v"(w4), "+v"(w5), "+v"(w6), "+v"(w7),                  \
                      "+v"(w8), "+v"(w9), "+v"(w10), "+v"(w11),                \
                      "+v"(w12), "+v"(w13), "+v"(w14), "+v"(w15));

#define MV(Q, W)                                      \
        a0 = fmaf(W.x, bcast(h, 4 * Q + 0), a0);      \
        a1 = fmaf(W.y, bcast(h, 4 * Q + 1), a1);      \
        a2 = fmaf(W.z, bcast(h, 4 * Q + 2), a2);      \
        a3 = fmaf(W.w, bcast(h, 4 * Q + 3), a3);

#define MV_ALL                                        \
        MV(0, w0)   MV(1, w1)   MV(2, w2)   MV(3, w3) \
        MV(4, w4)   MV(5, w5)   MV(6, w6)   MV(7, w7) \
        MV(8, w8)   MV(9, w9)   MV(10, w10) MV(11, w11) \
        MV(12, w12) MV(13, w13) MV(14, w14) MV(15, w15)

// =============== PROBE 1: matvec only (no LDS/barrier/trans) ===============
// dur/10 = 96-step cost of the matvec if exchange were free.
// Resident weights -> ~110-160us; spilled -> >=700us.
__global__ __launch_bounds__(256, 1)
__attribute__((amdgpu_waves_per_eu(1, 1)))
void probe_matvec(const float* __restrict__ Whh,
                  const float* __restrict__ h0,
                  float* __restrict__ sink) {
    const int tid  = threadIdx.x;
    const int lane = tid & 63;

    LOAD_W_AND_PIN(Whh)

    float h = h0[lane];
#pragma unroll 1
    for (int t = 0; t < PSTEPS; ++t) {
        float a0 = 0.f, a1 = 0.f, a2 = 0.f, a3 = 0.f;
        MV_ALL
        h = fmaf((a0 + a1) + (a2 + a3), 6.1e-5f, 1.0f);  // bounded, loop-carried
    }
    sink[tid] = h;   // flat[0..255], overwritten by linear1 later
}

// =============== PROBE 2: exchange only (no matvec) ===============
// activation + gate LDS write + barrier + gate reads + c/h update.
// dur/10 = 96-step cost of the exchange if the matvec were free.
__global__ __launch_bounds__(256, 1)
__attribute__((amdgpu_waves_per_eu(1, 1)))
void probe_exchange(const float* __restrict__ h0,
                    const float* __restrict__ c0,
                    const float* __restrict__ bih,
                    const float* __restrict__ bhh,
                    float* __restrict__ sink) {
    __shared__ float g_s[2][4 * HID];

    const int tid  = threadIdx.x;
    const int lane = tid & 63;
    const int wv   = tid >> 6;

    const float bias = bih[tid] + bhh[tid];
    float h = h0[lane];
    float c = c0[lane];
    __syncthreads();

#pragma unroll 1
    for (int t = 0; t < PSTEPS; ++t) {
        const int b = t & 1;
        const float pre = fmaf(h, 0.001f, bias);     // dep on h, no matvec
        const float act = (wv == 2) ? fast_tanh(pre) : fast_sigmoid(pre);
        g_s[b][tid] = act;
        __syncthreads();
        const float ig = g_s[b][lane];
        const float fg = g_s[b][HID + lane];
        const float gg = g_s[b][2 * HID + lane];
        const float og = g_s[b][3 * HID + lane];
        c = fmaf(fg, c, ig * gg);
        h = og * fast_tanh(c);
    }
    sink[256 + tid];   // no-op read avoided; real write below
    sink[256 + tid] = h + c;   // flat[256..511], overwritten by linear1 later
}

// ======================= REAL KERNELS (r8, unchanged) =======================
__global__ __launch_bounds__(256, 1)
__attribute__((amdgpu_waves_per_eu(1, 1)))
void lstm_fused(
    const float* __restrict__ x,     // (96, 5)
    const float* __restrict__ h0,    // (64)
    const float* __restrict__ c0,    // (64)
    const float* __restrict__ Wih,   // (256, 5)
    const float* __restrict__ Whh,   // (256, 64)
    const float* __restrict__ bih,   // (256)
    const float* __restrict__ bhh,   // (256)
    const float* __restrict__ W1,    // (96, 64)
    const float* __restrict__ b1,    // (96)
    float* __restrict__ flat_out)    // (9216) workspace
{
    __shared__ float x_s[TSEQ * NIN];
    __shared__ float g_s[2][4 * HID];
    __shared__ float hseq[TSEQ][HID];

    const int tid  = threadIdx.x;
    const int lane = tid & 63;
    const int wv   = tid >> 6;

    for (int i = tid; i < TSEQ * NIN; i += 256) x_s[i] = x[i];

    LOAD_W_AND_PIN(Whh)

    const float wi0 = Wih[tid * NIN + 0];
    const float wi1 = Wih[tid * NIN + 1];
    const float wi2 = Wih[tid * NIN + 2];
    const float wi3 = Wih[tid * NIN + 3];
    const float wi4 = Wih[tid * NIN + 4];
    const float bias = bih[tid] + bhh[tid];

    float h = h0[lane];
    float c = c0[lane];

    __syncthreads();

#pragma unroll 1
    for (int t = 0; t < TSEQ; ++t) {
        const int b = t & 1;
        const float xt0 = x_s[t * NIN + 0];
        const float xt1 = x_s[t * NIN + 1];
        const float xt2 = x_s[t * NIN + 2];
        const float xt3 = x_s[t * NIN + 3];
        const float xt4 = x_s[t * NIN + 4];
        float a0 = fmaf(wi0, xt0, bias);
        float a1 = wi1 * xt1;
        float a2 = wi2 * xt2;
        float a3 = wi3 * xt3;
        a0 = fmaf(wi4, xt4, a0);

        MV_ALL

        const float pre = (a0 + a1) + (a2 + a3);
        const float act = (wv == 2) ? fast_tanh(pre) : fast_sigmoid(pre);
        g_s[b][tid] = act;
        __syncthreads();

        const float ig = g_s[b][lane];
        const float fg = g_s[b][HID + lane];
        const float gg = g_s[b][2 * HID + lane];
        const float og = g_s[b][3 * HID + lane];
        c = fmaf(fg, c, ig * gg);
        h = og * fast_tanh(c);
        if (wv == 0) hseq[t][lane] = h;
    }

    __syncthreads();

    // linear1
    {
        const float4* __restrict__ W1v = reinterpret_cast<const float4*>(W1);
#pragma unroll 1
        for (int i = 0; i < FLATN / 256; ++i) {
            const int idx = tid + i * 256;
            const int t = idx / NOUT;
            const int k = idx - t * NOUT;
            const float4* hv = reinterpret_cast<const float4*>(&hseq[t][0]);
            float s0 = 0.f, s1 = 0.f, s2 = 0.f, s3 = 0.f;
#pragma unroll
            for (int j4 = 0; j4 < 16; ++j4) {
                const float4 a = W1v[k * 16 + j4];
                const float4 hb = hv[j4];
                s0 = fmaf(a.x, hb.x, s0);
                s1 = fmaf(a.y, hb.y, s1);
                s2 = fmaf(a.z, hb.z, s2);
                s3 = fmaf(a.w, hb.w, s3);
            }
            flat_out[idx] = b1[k] + ((s0 + s1) + (s2 + s3));
        }
    }
}

__global__ __launch_bounds__(256) void gemv_final_kernel(
    const float* __restrict__ W2,    // (96, 9216)
    const float* __restrict__ b2,    // (96)
    const float* __restrict__ flat,  // (9216)
    float* __restrict__ out)         // (96)
{
    const int o = blockIdx.x;
    const int tid = threadIdx.x;
    const float* __restrict__ row = &W2[o * FLATN];

    float s = 0.f;
#pragma unroll 4
    for (int j = tid; j < FLATN; j += 256) {
        s += row[j] * flat[j];
    }

#pragma unroll
    for (int off = 32; off > 0; off >>= 1) s += __shfl_down(s, off, 64);

    __shared__ float partial[4];
    if ((tid & 63) == 0) partial[tid >> 6] = s;
    __syncthreads();
    if (tid == 0) {
        out[o] = b2[o] + ((partial[0] + partial[1]) + (partial[2] + partial[3]));
    }
}

extern "C" void kernel_launch(void* const* d_in, const int* in_sizes, int n_in,
                              void* d_out, int out_size, void* d_ws, size_t ws_size,
                              hipStream_t stream) {
    const float* x   = (const float*)d_in[0];
    const float* h0  = (const float*)d_in[1];
    const float* c0  = (const float*)d_in[2];
    const float* Wih = (const float*)d_in[3];
    const float* Whh = (const float*)d_in[4];
    const float* bih = (const float*)d_in[5];
    const float* bhh = (const float*)d_in[6];
    const float* W1  = (const float*)d_in[7];
    const float* b1  = (const float*)d_in[8];
    const float* W2  = (const float*)d_in[9];
    const float* b2  = (const float*)d_in[10];

    float* out  = (float*)d_out;
    float* flat = (float*)d_ws;   // 9216 floats

    // Ablation probes first; their sinks (flat[0..511]) are fully
    // overwritten by lstm_fused's linear1, so correctness is unchanged.
    probe_matvec<<<1, 256, 0, stream>>>(Whh, h0, flat);
    probe_exchange<<<1, 256, 0, stream>>>(h0, c0, bih, bhh, flat);

    lstm_fused<<<1, 256, 0, stream>>>(x, h0, c0, Wih, Whh, bih, bhh, W1, b1, flat);
    gemv_final_kernel<<<NOUT, 256, 0, stream>>>(W2, b2, flat, out);
}

// Round 14
// 142.161 us; speedup vs baseline: 3.7758x; 3.7758x over previous
//
#include <hip/hip_runtime.h>
#include <hip/hip_bf16.h>
#include <math.h>

#define HID 64
#define TSEQ 96
#define NOUT 96
#define NIN 5
#define FLATN (TSEQ * NOUT)   // 9216

#define LOG2E 1.4426950408889634f

typedef float f32x4 __attribute__((ext_vector_type(4)));

// raw v_exp_f32 / v_rcp_f32 (~1 ulp) — avoids IEEE fdiv sequence
__device__ __forceinline__ float fast_sigmoid(float x) {
    return __builtin_amdgcn_rcpf(1.0f + __builtin_amdgcn_exp2f(-LOG2E * x));
}

__device__ __forceinline__ float fast_tanh(float x) {
    const float ax = fabsf(x);
    const float e = __builtin_amdgcn_exp2f(-2.0f * LOG2E * ax);
    const float t = (1.0f - e) * __builtin_amdgcn_rcpf(1.0f + e);
    return copysignf(t, x);
}

// Broadcast lane l's value of v to all lanes (v_readlane -> SGPR)
__device__ __forceinline__ float bcast(float v, int l) {
    return __uint_as_float(__builtin_amdgcn_readlane(__float_as_uint(v), l));
}

// W_hh row -> 16 named f32x4 values FORCED INTO AGPRs ("a" constraint).
// r12 probe: AGPR-parked weights run the matvec at 226 ns/step; the full
// kernel at 1400 ns/step is consistent with the allocator choosing SCRATCH
// under higher pressure. "a" removes that choice.
#define LOAD_W_AND_PIN(SRC)                                                    \
    const f32x4* __restrict__ Wrow = reinterpret_cast<const f32x4*>((SRC) + tid * HID); \
    f32x4 w0 = Wrow[0],  w1 = Wrow[1],  w2 = Wrow[2],  w3 = Wrow[3];           \
    f32x4 w4 = Wrow[4],  w5 = Wrow[5],  w6 = Wrow[6],  w7 = Wrow[7];           \
    f32x4 w8 = Wrow[8],  w9 = Wrow[9],  w10 = Wrow[10], w11 = Wrow[11];        \
    f32x4 w12 = Wrow[12], w13 = Wrow[13], w14 = Wrow[14], w15 = Wrow[15];      \
    asm volatile("" : "+a"(w0), "+a"(w1), "+a"(w2), "+a"(w3),                  \
                      "+a"(w4), "+a"(w5), "+a"(w6), "+a"(w7));                 \
    asm volatile("" : "+a"(w8), "+a"(w9), "+a"(w10), "+a"(w11),                \
                      "+a"(w12), "+a"(w13), "+a"(w14), "+a"(w15));

#define MV(Q, W)                                      \
        a0 = fmaf(W.x, bcast(h, 4 * Q + 0), a0);      \
        a1 = fmaf(W.y, bcast(h, 4 * Q + 1), a1);      \
        a2 = fmaf(W.z, bcast(h, 4 * Q + 2), a2);      \
        a3 = fmaf(W.w, bcast(h, 4 * Q + 3), a3);

#define MV_ALL                                        \
        MV(0, w0)   MV(1, w1)   MV(2, w2)   MV(3, w3) \
        MV(4, w4)   MV(5, w5)   MV(6, w6)   MV(7, w7) \
        MV(8, w8)   MV(9, w9)   MV(10, w10) MV(11, w11) \
        MV(12, w12) MV(13, w13) MV(14, w14) MV(15, w15)

// One block, 256 threads = 4 waves. Thread tid owns gate row tid.
// Weights in AGPRs; h,c replicated lane-distributed; gates exchanged via
// double-buffered LDS with one barrier per step.
__global__ __launch_bounds__(256, 1)
__attribute__((amdgpu_waves_per_eu(1, 1)))
void lstm_fused(
    const float* __restrict__ x,     // (96, 5)
    const float* __restrict__ h0,    // (64)
    const float* __restrict__ c0,    // (64)
    const float* __restrict__ Wih,   // (256, 5)
    const float* __restrict__ Whh,   // (256, 64)
    const float* __restrict__ bih,   // (256)
    const float* __restrict__ bhh,   // (256)
    const float* __restrict__ W1,    // (96, 64)
    const float* __restrict__ b1,    // (96)
    float* __restrict__ flat_out)    // (9216) workspace
{
    __shared__ float x_s[TSEQ * NIN];
    __shared__ float g_s[2][4 * HID];
    __shared__ float hseq[TSEQ][HID];

    const int tid  = threadIdx.x;
    const int lane = tid & 63;
    const int wv   = tid >> 6;

    for (int i = tid; i < TSEQ * NIN; i += 256) x_s[i] = x[i];

    LOAD_W_AND_PIN(Whh)

    const float wi0 = Wih[tid * NIN + 0];
    const float wi1 = Wih[tid * NIN + 1];
    const float wi2 = Wih[tid * NIN + 2];
    const float wi3 = Wih[tid * NIN + 3];
    const float wi4 = Wih[tid * NIN + 4];
    const float bias = bih[tid] + bhh[tid];

    float h = h0[lane];
    float c = c0[lane];

    __syncthreads();

#pragma unroll 1
    for (int t = 0; t < TSEQ; ++t) {
        const int b = t & 1;
        const float xt0 = x_s[t * NIN + 0];
        const float xt1 = x_s[t * NIN + 1];
        const float xt2 = x_s[t * NIN + 2];
        const float xt3 = x_s[t * NIN + 3];
        const float xt4 = x_s[t * NIN + 4];
        float a0 = fmaf(wi0, xt0, bias);
        float a1 = wi1 * xt1;
        float a2 = wi2 * xt2;
        float a3 = wi3 * xt3;
        a0 = fmaf(wi4, xt4, a0);

        MV_ALL

        const float pre = (a0 + a1) + (a2 + a3);
        const float act = (wv == 2) ? fast_tanh(pre) : fast_sigmoid(pre);
        g_s[b][tid] = act;
        __syncthreads();

        const float ig = g_s[b][lane];
        const float fg = g_s[b][HID + lane];
        const float gg = g_s[b][2 * HID + lane];
        const float og = g_s[b][3 * HID + lane];
        c = fmaf(fg, c, ig * gg);
        h = og * fast_tanh(c);
        if (wv == 0) hseq[t][lane] = h;
        // next step writes g_s[b^1]; g_s[b] reused at t+2, separated from
        // these reads by step t+1's barrier.
    }

    __syncthreads();

    // ---- linear1: flat[t*96 + k] = b1[k] + W1[k,:] . hseq[t,:] ----
    {
        const float4* __restrict__ W1v = reinterpret_cast<const float4*>(W1);
#pragma unroll 1
        for (int i = 0; i < FLATN / 256; ++i) {      // 36 iterations
            const int idx = tid + i * 256;
            const int t = idx / NOUT;
            const int k = idx - t * NOUT;
            const float4* hv = reinterpret_cast<const float4*>(&hseq[t][0]);
            float s0 = 0.f, s1 = 0.f, s2 = 0.f, s3 = 0.f;
#pragma unroll
            for (int j4 = 0; j4 < 16; ++j4) {
                const float4 a = W1v[k * 16 + j4];
                const float4 hb = hv[j4];
                s0 = fmaf(a.x, hb.x, s0);
                s1 = fmaf(a.y, hb.y, s1);
                s2 = fmaf(a.z, hb.z, s2);
                s3 = fmaf(a.w, hb.w, s3);
            }
            flat_out[idx] = b1[k] + ((s0 + s1) + (s2 + s3));
        }
    }
}

// Kernel 2: out[o] = b2[o] + W2[o,:] . flat   (96 blocks, one output each)
__global__ __launch_bounds__(256) void gemv_final_kernel(
    const float* __restrict__ W2,    // (96, 9216)
    const float* __restrict__ b2,    // (96)
    const float* __restrict__ flat,  // (9216)
    float* __restrict__ out)         // (96)
{
    const int o = blockIdx.x;
    const int tid = threadIdx.x;
    const float* __restrict__ row = &W2[o * FLATN];

    float s = 0.f;
#pragma unroll 4
    for (int j = tid; j < FLATN; j += 256) {
        s += row[j] * flat[j];
    }

#pragma unroll
    for (int off = 32; off > 0; off >>= 1) s += __shfl_down(s, off, 64);

    __shared__ float partial[4];
    if ((tid & 63) == 0) partial[tid >> 6] = s;
    __syncthreads();
    if (tid == 0) {
        out[o] = b2[o] + ((partial[0] + partial[1]) + (partial[2] + partial[3]));
    }
}

extern "C" void kernel_launch(void* const* d_in, const int* in_sizes, int n_in,
                              void* d_out, int out_size, void* d_ws, size_t ws_size,
                              hipStream_t stream) {
    const float* x   = (const float*)d_in[0];
    const float* h0  = (const float*)d_in[1];
    const float* c0  = (const float*)d_in[2];
    const float* Wih = (const float*)d_in[3];
    const float* Whh = (const float*)d_in[4];
    const float* bih = (const float*)d_in[5];
    const float* bhh = (const float*)d_in[6];
    const float* W1  = (const float*)d_in[7];
    const float* b1  = (const float*)d_in[8];
    const float* W2  = (const float*)d_in[9];
    const float* b2  = (const float*)d_in[10];

    float* out  = (float*)d_out;
    float* flat = (float*)d_ws;   // 9216 floats

    lstm_fused<<<1, 256, 0, stream>>>(x, h0, c0, Wih, Whh, bih, bhh, W1, b1, flat);
    gemv_final_kernel<<<NOUT, 256, 0, stream>>>(W2, b2, flat, out);
}

// Round 15
// 140.397 us; speedup vs baseline: 3.8232x; 1.0126x over previous
//
#include <hip/hip_runtime.h>
#include <hip/hip_bf16.h>
#include <math.h>

#define HID 64
#define TSEQ 96
#define NOUT 96
#define NIN 5
#define FLATN (TSEQ * NOUT)   // 9216

#define LOG2E 1.4426950408889634f

typedef float f32x4 __attribute__((ext_vector_type(4)));

__device__ __forceinline__ float fast_sigmoid(float x) {
    return __builtin_amdgcn_rcpf(1.0f + __builtin_amdgcn_exp2f(-LOG2E * x));
}

__device__ __forceinline__ float fast_tanh(float x) {
    const float ax = fabsf(x);
    const float e = __builtin_amdgcn_exp2f(-2.0f * LOG2E * ax);
    const float t = (1.0f - e) * __builtin_amdgcn_rcpf(1.0f + e);
    return copysignf(t, x);
}

__device__ __forceinline__ float bcast(float v, int l) {
    return __uint_as_float(__builtin_amdgcn_readlane(__float_as_uint(v), l));
}

// W_hh row -> 16 named f32x4 values in AGPRs (r14: allocation verified by
// VGPR 44->76 shift; timing-neutral, kept because it frees VGPR budget).
#define LOAD_W_AND_PIN(SRC)                                                    \
    const f32x4* __restrict__ Wrow = reinterpret_cast<const f32x4*>((SRC) + tid * HID); \
    f32x4 w0 = Wrow[0],  w1 = Wrow[1],  w2 = Wrow[2],  w3 = Wrow[3];           \
    f32x4 w4 = Wrow[4],  w5 = Wrow[5],  w6 = Wrow[6],  w7 = Wrow[7];           \
    f32x4 w8 = Wrow[8],  w9 = Wrow[9],  w10 = Wrow[10], w11 = Wrow[11];        \
    f32x4 w12 = Wrow[12], w13 = Wrow[13], w14 = Wrow[14], w15 = Wrow[15];      \
    asm volatile("" : "+a"(w0), "+a"(w1), "+a"(w2), "+a"(w3),                  \
                      "+a"(w4), "+a"(w5), "+a"(w6), "+a"(w7));                 \
    asm volatile("" : "+a"(w8), "+a"(w9), "+a"(w10), "+a"(w11),                \
                      "+a"(w12), "+a"(w13), "+a"(w14), "+a"(w15));

#define MV(Q, W)                                      \
        a0 = fmaf(W.x, bcast(h, 4 * Q + 0), a0);      \
        a1 = fmaf(W.y, bcast(h, 4 * Q + 1), a1);      \
        a2 = fmaf(W.z, bcast(h, 4 * Q + 2), a2);      \
        a3 = fmaf(W.w, bcast(h, 4 * Q + 3), a3);

#define MV_ALL                                        \
        MV(0, w0)   MV(1, w1)   MV(2, w2)   MV(3, w3) \
        MV(4, w4)   MV(5, w5)   MV(6, w6)   MV(7, w7) \
        MV(8, w8)   MV(9, w9)   MV(10, w10) MV(11, w11) \
        MV(12, w12) MV(13, w13) MV(14, w14) MV(15, w15)

// One block, 256 threads = 4 waves. Thread tid owns gate row tid.
// Weights in AGPRs; h,c replicated lane-distributed; one barrier/step.
// NEW (r15): x_t+1 is prefetched into registers at the top of step t --
// the 5 uniform-address ds_read broadcasts are off the critical path
// (they complete under the matvec+exchange of the current step).
__global__ __launch_bounds__(256, 1)
__attribute__((amdgpu_waves_per_eu(1, 1)))
void lstm_fused(
    const float* __restrict__ x,     // (96, 5)
    const float* __restrict__ h0,    // (64)
    const float* __restrict__ c0,    // (64)
    const float* __restrict__ Wih,   // (256, 5)
    const float* __restrict__ Whh,   // (256, 64)
    const float* __restrict__ bih,   // (256)
    const float* __restrict__ bhh,   // (256)
    const float* __restrict__ W1,    // (96, 64)
    const float* __restrict__ b1,    // (96)
    float* __restrict__ flat_out)    // (9216) workspace
{
    __shared__ float x_s[TSEQ * NIN];
    __shared__ float g_s[2][4 * HID];
    __shared__ float hseq[TSEQ][HID];

    const int tid  = threadIdx.x;
    const int lane = tid & 63;
    const int wv   = tid >> 6;

    for (int i = tid; i < TSEQ * NIN; i += 256) x_s[i] = x[i];

    LOAD_W_AND_PIN(Whh)

    const float wi0 = Wih[tid * NIN + 0];
    const float wi1 = Wih[tid * NIN + 1];
    const float wi2 = Wih[tid * NIN + 2];
    const float wi3 = Wih[tid * NIN + 3];
    const float wi4 = Wih[tid * NIN + 4];
    const float bias = bih[tid] + bhh[tid];

    float h = h0[lane];
    float c = c0[lane];

    __syncthreads();

    // prefetch x_0
    float nx0 = x_s[0], nx1 = x_s[1], nx2 = x_s[2], nx3 = x_s[3], nx4 = x_s[4];

#pragma unroll 1
    for (int t = 0; t < TSEQ; ++t) {
        const int b = t & 1;
        // consume prefetched x_t
        const float xt0 = nx0, xt1 = nx1, xt2 = nx2, xt3 = nx3, xt4 = nx4;
        // issue prefetch for x_{t+1}; first use is next iteration's a-init,
        // so the LDS latency hides under this step's matvec+exchange.
        const int tn = (t + 1 < TSEQ) ? (t + 1) : t;
        nx0 = x_s[tn * NIN + 0];
        nx1 = x_s[tn * NIN + 1];
        nx2 = x_s[tn * NIN + 2];
        nx3 = x_s[tn * NIN + 3];
        nx4 = x_s[tn * NIN + 4];

        float a0 = fmaf(wi0, xt0, bias);
        float a1 = wi1 * xt1;
        float a2 = wi2 * xt2;
        float a3 = wi3 * xt3;
        a0 = fmaf(wi4, xt4, a0);

        MV_ALL

        const float pre = (a0 + a1) + (a2 + a3);
        const float act = (wv == 2) ? fast_tanh(pre) : fast_sigmoid(pre);
        g_s[b][tid] = act;
        __syncthreads();

        const float ig = g_s[b][lane];
        const float fg = g_s[b][HID + lane];
        const float gg = g_s[b][2 * HID + lane];
        const float og = g_s[b][3 * HID + lane];
        c = fmaf(fg, c, ig * gg);
        h = og * fast_tanh(c);
        if (wv == 0) hseq[t][lane] = h;
        // next step writes g_s[b^1]; g_s[b] reused at t+2, separated from
        // these reads by step t+1's barrier.
    }

    __syncthreads();

    // ---- linear1: flat[t*96 + k] = b1[k] + W1[k,:] . hseq[t,:] ----
    {
        const float4* __restrict__ W1v = reinterpret_cast<const float4*>(W1);
#pragma unroll 1
        for (int i = 0; i < FLATN / 256; ++i) {      // 36 iterations
            const int idx = tid + i * 256;
            const int t = idx / NOUT;
            const int k = idx - t * NOUT;
            const float4* hv = reinterpret_cast<const float4*>(&hseq[t][0]);
            float s0 = 0.f, s1 = 0.f, s2 = 0.f, s3 = 0.f;
#pragma unroll
            for (int j4 = 0; j4 < 16; ++j4) {
                const float4 a = W1v[k * 16 + j4];
                const float4 hb = hv[j4];
                s0 = fmaf(a.x, hb.x, s0);
                s1 = fmaf(a.y, hb.y, s1);
                s2 = fmaf(a.z, hb.z, s2);
                s3 = fmaf(a.w, hb.w, s3);
            }
            flat_out[idx] = b1[k] + ((s0 + s1) + (s2 + s3));
        }
    }
}

// Kernel 2: out[o] = b2[o] + W2[o,:] . flat   (96 blocks, one output each)
__global__ __launch_bounds__(256) void gemv_final_kernel(
    const float* __restrict__ W2,    // (96, 9216)
    const float* __restrict__ b2,    // (96)
    const float* __restrict__ flat,  // (9216)
    float* __restrict__ out)         // (96)
{
    const int o = blockIdx.x;
    const int tid = threadIdx.x;
    const float* __restrict__ row = &W2[o * FLATN];

    float s = 0.f;
#pragma unroll 4
    for (int j = tid; j < FLATN; j += 256) {
        s += row[j] * flat[j];
    }

#pragma unroll
    for (int off = 32; off > 0; off >>= 1) s += __shfl_down(s, off, 64);

    __shared__ float partial[4];
    if ((tid & 63) == 0) partial[tid >> 6] = s;
    __syncthreads();
    if (tid == 0) {
        out[o] = b2[o] + ((partial[0] + partial[1]) + (partial[2] + partial[3]));
    }
}

extern "C" void kernel_launch(void* const* d_in, const int* in_sizes, int n_in,
                              void* d_out, int out_size, void* d_ws, size_t ws_size,
                              hipStream_t stream) {
    const float* x   = (const float*)d_in[0];
    const float* h0  = (const float*)d_in[1];
    const float* c0  = (const float*)d_in[2];
    const float* Wih = (const float*)d_in[3];
    const float* Whh = (const float*)d_in[4];
    const float* bih = (const float*)d_in[5];
    const float* bhh = (const float*)d_in[6];
    const float* W1  = (const float*)d_in[7];
    const float* b1  = (const float*)d_in[8];
    const float* W2  = (const float*)d_in[9];
    const float* b2  = (const float*)d_in[10];

    float* out  = (float*)d_out;
    float* flat = (float*)d_ws;   // 9216 floats

    lstm_fused<<<1, 256, 0, stream>>>(x, h0, c0, Wih, Whh, bih, bhh, W1, b1, flat);
    gemv_final_kernel<<<NOUT, 256, 0, stream>>>(W2, b2, flat, out);
}